// Round 7
// baseline (16500.801 us; speedup 1.0000x reference)
//
#include <hip/hip_runtime.h>

// Problem dims
#define T_ 128
#define B_ 64
#define E_ 256
#define H_ 512
#define S_ 1024
#define G_ 2048            // 4H
#define NCH 6              // attention s-chunks per batch row
#define NBLK 512
#define ABLK 128           // blocks doing LSTM (A) + output heads (C)
#define BLK 256
#define NGRP 16            // broadcast "go" lines
#define BH (B_*H_)
#define PSTR 520
#define PARTBUF (B_*NCH*PSTR)

// ---- barrier area (uint indices into ws) ----
#define U_ARR   256
#define U_TOTAL (U_ARR + NBLK*16)

// ws layout (float indices)
#define F_V1   8704                     // 512: Wpg[0:512] + Wax_top @ w4
#define F_VX   (F_V1 + 512)             // 256: Wax_bot @ w4
#define F_S0   (F_VX + 256)             // 1 (+63 pad)
#define F_H3   (F_S0 + 64)              // 3*B*H (h_t at slot t%3; h0 at slot 2)
#define F_C3   (F_H3 + 3*BH)
#define F_SC2  (F_C3 + 3*BH)            // 2*B*S raw scores (double buffer)
#define F_PART (F_SC2 + 2*B_*S_)        // 2*PARTBUF {m,l,pad6,ctx[512]}
#define F_CTX16 (F_PART + 2*PARTBUF)    // float idx where bf16 ctx copy begins
#define WS_MIN_BYTES ((size_t)F_CTX16*4)
#define WS_BF16_BYTES ((size_t)F_CTX16*4 + (size_t)B_*S_*H_*2)

// out layout (float indices)
#define O_OUT 0
#define O_H   ((size_t)T_*B_*H_)
#define O_C   (O_H + BH)
#define O_AD  (O_C + BH)
#define O_PG  (O_AD + (size_t)T_*B_*S_)

// LDS pool (floats). A: [0,5136). B: [0,2260). C: [5136,7200).
#define S_ACT   0        // A: 4 x 772 (x:0..256, h:256..768)
#define S_PART  3088     // A: 4 x 64 x 4
#define S_GATE  4112     // A: 4 x 256
#define SB_RED  0        // B: 4 x 520
#define SB_ML   2080     // B: 8
#define SB_BIAS 2088     // B: 172 (persists across steps on B-blocks)
#define C_ACTX  5136     // C: 512
#define C_H2    5648     // C: 512
#define C_PRT   6160     // C: 256
#define C_TMP   6416     // C: 8
#define C_V1    6424     // C: 769 (V1 512 | VX 256 | S0 1) — persists
#define POOLSZ  7200

#define NEG_INF (-__builtin_inff())

__device__ __forceinline__ float sigm(float x){ return 1.f/(1.f+__expf(-x)); }
__device__ __forceinline__ float tanh_(float x){ return 1.f - 2.f/(1.f+__expf(2.f*x)); }
__device__ __forceinline__ float wred(float v){
#pragma unroll
  for (int m = 1; m < 64; m <<= 1) v += __shfl_xor(v, m, 64);
  return v;
}
// device-coherent (sc1) access — for data mutated across blocks during the run
__device__ __forceinline__ float ald(const float* p){
  return __hip_atomic_load(p, __ATOMIC_RELAXED, __HIP_MEMORY_SCOPE_AGENT);
}
__device__ __forceinline__ void ast(float* p, float v){
  __hip_atomic_store(p, v, __ATOMIC_RELAXED, __HIP_MEMORY_SCOPE_AGENT);
}
__device__ __forceinline__ void ast64(unsigned long long* p, unsigned long long v){
  __hip_atomic_store(p, v, __ATOMIC_RELAXED, __HIP_MEMORY_SCOPE_AGENT);
}
__device__ __forceinline__ unsigned short b16rne(float f){
  unsigned u = __float_as_uint(f);
  unsigned r = u + 0x7fffu + ((u >> 16) & 1u);
  return (unsigned short)(r >> 16);
}
// unpack 2 bf16 from one u32 (little-endian packing: elem0 = low 16 bits)
__device__ __forceinline__ void unp(unsigned w, float& lo, float& hi){
  lo = __uint_as_float(w << 16);
  hi = __uint_as_float(w & 0xffff0000u);
}

// ---- fence-free grid barrier (512 blocks; sc1 data => no cache fences) ----
__device__ __forceinline__ void gbar(unsigned* W, unsigned ep){
  __syncthreads();
  const int tid = threadIdx.x, bid = blockIdx.x;
  if (tid == 0) {
    asm volatile("s_waitcnt vmcnt(0)" ::: "memory");
    __hip_atomic_store(&W[U_ARR + bid*16], ep, __ATOMIC_RELAXED, __HIP_MEMORY_SCOPE_AGENT);
  }
  if (bid == 0) {
    const int i0 = tid*2, i1 = i0+1;
    while (__hip_atomic_load(&W[U_ARR + i0*16], __ATOMIC_RELAXED, __HIP_MEMORY_SCOPE_AGENT) < ep)
      __builtin_amdgcn_s_sleep(2);
    while (__hip_atomic_load(&W[U_ARR + i1*16], __ATOMIC_RELAXED, __HIP_MEMORY_SCOPE_AGENT) < ep)
      __builtin_amdgcn_s_sleep(2);
    __syncthreads();
    if (tid < NGRP)
      __hip_atomic_store(&W[tid*16], ep, __ATOMIC_RELAXED, __HIP_MEMORY_SCOPE_AGENT);
  }
  if (tid == 0) {
    while (__hip_atomic_load(&W[(bid>>5)*16], __ATOMIC_RELAXED, __HIP_MEMORY_SCOPE_AGENT) < ep)
      __builtin_amdgcn_s_sleep(4);
  }
  __syncthreads();
}

// ---------------- Phase A: LSTM cell for step t ----------------
// 128 blocks = 16 bg (4 b) x 8 ug (64 units = 256 gate-cols).
// thread = (ks[7] bl[6:5] cq[4:0]): split-K x2, 2 float4 col-groups, unroll 8.
__device__ void do_A(int t, int bid, int tid,
                     const float* __restrict__ emb, const float* __restrict__ Wih,
                     const float* __restrict__ bih, const float* __restrict__ Whh,
                     const float* __restrict__ bhh, float* __restrict__ F,
                     float* __restrict__ pool)
{
  const int bg = bid >> 3, ug = bid & 7;
  { // stage act[bl][0:256)=x, [256:768)=h_{t-1}
    const int r = tid >> 6, i = tid & 63;
    const float* xr = emb + ((size_t)(bg*4 + r)*T_ + t)*E_ + i*4;
    *(float4*)(pool + S_ACT + r*772 + i*4) = *(const float4*)xr;
    const float* hsrc = F + F_H3 + ((t+2)%3)*BH + (size_t)(bg*4 + r)*H_ + i*8;
    float4 h0v, h1v;
    h0v.x=ald(hsrc+0); h0v.y=ald(hsrc+1); h0v.z=ald(hsrc+2); h0v.w=ald(hsrc+3);
    h1v.x=ald(hsrc+4); h1v.y=ald(hsrc+5); h1v.z=ald(hsrc+6); h1v.w=ald(hsrc+7);
    *(float4*)(pool + S_ACT + r*772 + 256 + i*8)     = h0v;
    *(float4*)(pool + S_ACT + r*772 + 256 + i*8 + 4) = h1v;
  }
  __syncthreads();
  const int ks = tid >> 7, bl = (tid >> 5) & 3, cq = tid & 31;
  const int cgi1 = cq, cgi2 = cq + 32;
  const int col1 = ((cgi1 >> 4) << 9) + ug*64 + ((cgi1 & 15) << 2);
  const int col2 = ((cgi2 >> 4) << 9) + ug*64 + ((cgi2 & 15) << 2);
  float4 A1, A2;
  if (ks == 0) {
    const float4 x1 = *(const float4*)(bih + col1), y1 = *(const float4*)(bhh + col1);
    const float4 x2 = *(const float4*)(bih + col2), y2 = *(const float4*)(bhh + col2);
    A1.x=x1.x+y1.x; A1.y=x1.y+y1.y; A1.z=x1.z+y1.z; A1.w=x1.w+y1.w;
    A2.x=x2.x+y2.x; A2.y=x2.y+y2.y; A2.z=x2.z+y2.z; A2.w=x2.w+y2.w;
  } else { A1.x=A1.y=A1.z=A1.w=0.f; A2.x=A2.y=A2.z=A2.w=0.f; }
  const float* ap = pool + S_ACT + bl*772;
  if (ks == 0) {
    const float* w1 = Wih + col1; const float* w2 = Wih + col2;
#pragma unroll 8
    for (int k = 0; k < 256; ++k) {
      float a = ap[k];
      float4 v1 = *(const float4*)(w1 + (size_t)k*G_);
      float4 v2 = *(const float4*)(w2 + (size_t)k*G_);
      A1.x=fmaf(a,v1.x,A1.x); A1.y=fmaf(a,v1.y,A1.y); A1.z=fmaf(a,v1.z,A1.z); A1.w=fmaf(a,v1.w,A1.w);
      A2.x=fmaf(a,v2.x,A2.x); A2.y=fmaf(a,v2.y,A2.y); A2.z=fmaf(a,v2.z,A2.z); A2.w=fmaf(a,v2.w,A2.w);
    }
    const float* u1 = Whh + col1; const float* u2 = Whh + col2;
    const float* ap2 = ap + 256;
#pragma unroll 8
    for (int k = 0; k < 128; ++k) {
      float a = ap2[k];
      float4 v1 = *(const float4*)(u1 + (size_t)k*G_);
      float4 v2 = *(const float4*)(u2 + (size_t)k*G_);
      A1.x=fmaf(a,v1.x,A1.x); A1.y=fmaf(a,v1.y,A1.y); A1.z=fmaf(a,v1.z,A1.z); A1.w=fmaf(a,v1.w,A1.w);
      A2.x=fmaf(a,v2.x,A2.x); A2.y=fmaf(a,v2.y,A2.y); A2.z=fmaf(a,v2.z,A2.z); A2.w=fmaf(a,v2.w,A2.w);
    }
  } else {
    const float* u1 = Whh + (size_t)128*G_ + col1; const float* u2 = Whh + (size_t)128*G_ + col2;
    const float* ap2 = ap + 384;
#pragma unroll 8
    for (int k = 0; k < 384; ++k) {
      float a = ap2[k];
      float4 v1 = *(const float4*)(u1 + (size_t)k*G_);
      float4 v2 = *(const float4*)(u2 + (size_t)k*G_);
      A1.x=fmaf(a,v1.x,A1.x); A1.y=fmaf(a,v1.y,A1.y); A1.z=fmaf(a,v1.z,A1.z); A1.w=fmaf(a,v1.w,A1.w);
      A2.x=fmaf(a,v2.x,A2.x); A2.y=fmaf(a,v2.y,A2.y); A2.z=fmaf(a,v2.z,A2.z); A2.w=fmaf(a,v2.w,A2.w);
    }
  }
  if (ks == 1) {
    *(float4*)(pool + S_PART + ((bl*64 + cgi1) << 2)) = A1;
    *(float4*)(pool + S_PART + ((bl*64 + cgi2) << 2)) = A2;
  }
  __syncthreads();
  if (ks == 0) {
    const float4 P1 = *(const float4*)(pool + S_PART + ((bl*64 + cgi1) << 2));
    const float4 P2 = *(const float4*)(pool + S_PART + ((bl*64 + cgi2) << 2));
    A1.x+=P1.x; A1.y+=P1.y; A1.z+=P1.z; A1.w+=P1.w;
    A2.x+=P2.x; A2.y+=P2.y; A2.z+=P2.z; A2.w+=P2.w;
    *(float4*)(pool + S_GATE + bl*256 + (cgi1 << 2)) = A1;
    *(float4*)(pool + S_GATE + bl*256 + (cgi2 << 2)) = A2;
  }
  __syncthreads();
  { // nonlinearity: thread = (bl2, unit)
    const int bl2 = tid >> 6, ul = tid & 63;
    const int b2 = bg*4 + bl2, uu = ug*64 + ul;
    float gi = pool[S_GATE + bl2*256 + ul];
    float gf = pool[S_GATE + bl2*256 + 64 + ul];
    float gg = pool[S_GATE + bl2*256 + 128 + ul];
    float go = pool[S_GATE + bl2*256 + 192 + ul];
    float cp = ald(F + F_C3 + ((t+2)%3)*BH + (size_t)b2*H_ + uu);
    float cn = sigm(gf)*cp + sigm(gi)*tanh_(gg);
    float hn = sigm(go)*tanh_(cn);
    ast(F + F_H3 + (t%3)*BH + (size_t)b2*H_ + uu, hn);
    ast(F + F_C3 + (t%3)*BH + (size_t)b2*H_ + uu, cn);
  }
}

// ---------------- Phase B: single-pass attention partials for step t ----------------
// ctx16 is written ONCE in phase 0 (sc1 write-through, no dirty L2 lines) and only
// read after a grid barrier; no XCD touches it before -> NORMAL cached loads are
// safe and hit L2/L3 (64MB bf16 is L3-resident).
template<bool BF16>
__device__ void do_B(int t, int bid, int tid, const float* __restrict__ ctx,
                     float* __restrict__ F, float* __restrict__ pool)
{
  const int idx = bid - ABLK;
  const int b = idx / NCH, ch = idx - b*NCH;
  const int sb = (ch*S_)/NCH, se = ((ch+1)*S_)/NCH;
  const int w = tid >> 6, lane = tid & 63;
  const float* hb = F + F_H3 + (t%3)*BH + (size_t)b*H_ + lane*8;
  float h0_=ald(hb+0), h1_=ald(hb+1), h2_=ald(hb+2), h3_=ald(hb+3),
        h4_=ald(hb+4), h5_=ald(hb+5), h6_=ald(hb+6), h7_=ald(hb+7);
  float* scw = F + F_SC2 + (size_t)(t&1)*(B_*S_) + (size_t)b*S_;
  const float* s_bias = pool + SB_BIAS;
  const uint4* c16v = (const uint4*)(F + F_CTX16);   // row = 64 uint4
  const float* cbase = ctx + (size_t)b*S_*H_ + lane*8;
  float m = NEG_INF, l = 0.f;
  float a0=0,a1=0,a2=0,a3=0,a4=0,a5=0,a6=0,a7=0;
  for (int s0 = sb + w*4; s0 < se; s0 += 16) {
    float cv[4][8]; float d[4];
    if (BF16) {
      uint4 q[4];
#pragma unroll
      for (int i = 0; i < 4; ++i) {
        int s = s0 + i; int ss = (s < se) ? s : sb;
        q[i] = c16v[((size_t)b*S_ + ss)*64 + lane];   // normal cached 16B load
      }
#pragma unroll
      for (int i = 0; i < 4; ++i) {
        unp(q[i].x, cv[i][0], cv[i][1]);
        unp(q[i].y, cv[i][2], cv[i][3]);
        unp(q[i].z, cv[i][4], cv[i][5]);
        unp(q[i].w, cv[i][6], cv[i][7]);
      }
    } else {
#pragma unroll
      for (int i = 0; i < 4; ++i) {
        int s = s0 + i;
        const float* cr = cbase + (size_t)(s < se ? s : sb)*H_;
        float4 cA = *(const float4*)cr, cB = *(const float4*)(cr + 4);
        cv[i][0]=cA.x; cv[i][1]=cA.y; cv[i][2]=cA.z; cv[i][3]=cA.w;
        cv[i][4]=cB.x; cv[i][5]=cB.y; cv[i][6]=cB.z; cv[i][7]=cB.w;
      }
    }
#pragma unroll
    for (int i = 0; i < 4; ++i)
      d[i] = cv[i][0]*h0_ + cv[i][1]*h1_ + cv[i][2]*h2_ + cv[i][3]*h3_
           + cv[i][4]*h4_ + cv[i][5]*h5_ + cv[i][6]*h6_ + cv[i][7]*h7_;
#pragma unroll
    for (int mm = 1; mm < 64; mm <<= 1) {
      d[0] += __shfl_xor(d[0], mm, 64); d[1] += __shfl_xor(d[1], mm, 64);
      d[2] += __shfl_xor(d[2], mm, 64); d[3] += __shfl_xor(d[3], mm, 64);
    }
    float sc[4];
#pragma unroll
    for (int i = 0; i < 4; ++i) {
      int s = s0 + i;
      sc[i] = (s < se) ? d[i] + s_bias[s - sb] : NEG_INF;
      if (lane == 0 && s < se) ast(scw + s, sc[i]);
    }
    float mx = fmaxf(fmaxf(sc[0],sc[1]), fmaxf(sc[2],sc[3]));
    float mn = fmaxf(m, mx);
    float al = (mn == m) ? 1.f : __expf(m - mn);
    float w0 = (sc[0]==NEG_INF)?0.f:__expf(sc[0]-mn);
    float w1 = (sc[1]==NEG_INF)?0.f:__expf(sc[1]-mn);
    float w2 = (sc[2]==NEG_INF)?0.f:__expf(sc[2]-mn);
    float w3 = (sc[3]==NEG_INF)?0.f:__expf(sc[3]-mn);
    l = l*al + (w0+w1+w2+w3);
    a0 = a0*al + w0*cv[0][0] + w1*cv[1][0] + w2*cv[2][0] + w3*cv[3][0];
    a1 = a1*al + w0*cv[0][1] + w1*cv[1][1] + w2*cv[2][1] + w3*cv[3][1];
    a2 = a2*al + w0*cv[0][2] + w1*cv[1][2] + w2*cv[2][2] + w3*cv[3][2];
    a3 = a3*al + w0*cv[0][3] + w1*cv[1][3] + w2*cv[2][3] + w3*cv[3][3];
    a4 = a4*al + w0*cv[0][4] + w1*cv[1][4] + w2*cv[2][4] + w3*cv[3][4];
    a5 = a5*al + w0*cv[0][5] + w1*cv[1][5] + w2*cv[2][5] + w3*cv[3][5];
    a6 = a6*al + w0*cv[0][6] + w1*cv[1][6] + w2*cv[2][6] + w3*cv[3][6];
    a7 = a7*al + w0*cv[0][7] + w1*cv[1][7] + w2*cv[2][7] + w3*cv[3][7];
    m = mn;
  }
  if (lane == 0) { pool[SB_ML + w*2] = m; pool[SB_ML + w*2+1] = l; }
  { float* r = pool + SB_RED + w*520 + lane*8;
    r[0]=a0; r[1]=a1; r[2]=a2; r[3]=a3; r[4]=a4; r[5]=a5; r[6]=a6; r[7]=a7; }
  __syncthreads();
  float m0=pool[SB_ML+0], l0=pool[SB_ML+1], m1=pool[SB_ML+2], l1=pool[SB_ML+3],
        m2=pool[SB_ML+4], l2=pool[SB_ML+5], m3=pool[SB_ML+6], l3=pool[SB_ML+7];
  float mb = fmaxf(fmaxf(m0,m1), fmaxf(m2,m3));
  float k0 = (l0>0.f) ? __expf(m0-mb) : 0.f;
  float k1 = (l1>0.f) ? __expf(m1-mb) : 0.f;
  float k2 = (l2>0.f) ? __expf(m2-mb) : 0.f;
  float k3 = (l3>0.f) ? __expf(m3-mb) : 0.f;
  float lb = k0*l0 + k1*l1 + k2*l2 + k3*l3;
  float* Pp = F + F_PART + (size_t)(t&1)*PARTBUF + (size_t)(b*NCH+ch)*PSTR;
  for (int u = tid; u < H_; u += BLK)
    ast(Pp + 8 + u, k0*pool[SB_RED + 0*520 + u] + k1*pool[SB_RED + 1*520 + u]
                  + k2*pool[SB_RED + 2*520 + u] + k3*pool[SB_RED + 3*520 + u]);
  if (tid == 0) { ast(Pp+0, mb); ast(Pp+1, lb); }
}

// ---------------- Phase C: outputs for step tc ----------------
// 128 blocks: b = bid>>1, p = bid&1 (256-col slice). split-K x2 + 2 cols/thread.
__device__ void do_C(int tc, int bid, int tid,
                     const float* __restrict__ emb, const float* __restrict__ Wout,
                     const float* __restrict__ bout, const float* __restrict__ Wpg,
                     float* __restrict__ out, float* __restrict__ F,
                     float* __restrict__ pool)
{
  const int b = bid >> 1, p = bid & 1;
  const float* P0 = F + F_PART + (size_t)(tc&1)*PARTBUF + (size_t)(b*NCH)*PSTR;
  float mk[NCH], lk[NCH], ck[NCH];
  float mb = NEG_INF;
#pragma unroll
  for (int k = 0; k < NCH; ++k) { mk[k]=ald(P0+k*PSTR); lk[k]=ald(P0+k*PSTR+1); mb=fmaxf(mb,mk[k]); }
  float lb = 0.f;
#pragma unroll
  for (int k = 0; k < NCH; ++k) { ck[k] = (lk[k]>0.f) ? __expf(mk[k]-mb) : 0.f; lb += ck[k]*lk[k]; }
  float inv = 1.f/lb;
  { // merge partial contexts -> actx ; stage h
    int u = tid;
    float v0 = 0.f, v1 = 0.f;
#pragma unroll
    for (int k = 0; k < NCH; ++k) {
      v0 += ck[k]*ald(P0 + k*PSTR + 8 + u);
      v1 += ck[k]*ald(P0 + k*PSTR + 8 + u + 256);
    }
    pool[C_ACTX + u]       = v0*inv;
    pool[C_ACTX + u + 256] = v1*inv;
    const float* hsrc = F + F_H3 + (tc%3)*BH + (size_t)b*H_;
    pool[C_H2 + tid]       = ald(hsrc + tid);
    pool[C_H2 + tid + 256] = ald(hsrc + tid + 256);
  }
  __syncthreads();
  { // attention distribution (this block's 512-col slice of S)
    const float* scr = F + F_SC2 + (size_t)(tc&1)*(B_*S_) + (size_t)b*S_;
    float* ad = out + O_AD + ((size_t)tc*B_ + b)*S_;
    int s = p*512 + tid;
    ad[s] = __expf(ald(scr+s)-mb)*inv;
    s += 256;
    ad[s] = __expf(ald(scr+s)-mb)*inv;
  }
  { // out = [attn_ctx, h] @ W_out + b_out : kh=0 -> actx rows, kh=1 -> h rows
    const int kh = tid >> 7, jj = tid & 127;
    const int j = p*256 + jj;
    float acc0 = (kh == 0) ? bout[j]     : 0.f;
    float acc1 = (kh == 0) ? bout[j+128] : 0.f;
    const float* src = (kh == 0) ? (pool + C_ACTX) : (pool + C_H2);
    const float* wq = Wout + (size_t)(kh*512)*H_ + j;
#pragma unroll 8
    for (int k = 0; k < 512; ++k) {
      float s = src[k];
      const float* r = wq + (size_t)k*H_;
      acc0 = fmaf(s, r[0],   acc0);
      acc1 = fmaf(s, r[128], acc1);
    }
    if (kh == 1) { pool[C_PRT + jj*2] = acc0; pool[C_PRT + jj*2 + 1] = acc1; }
    __syncthreads();
    if (kh == 0) {
      acc0 += pool[C_PRT + jj*2];
      acc1 += pool[C_PRT + jj*2 + 1];
      out[O_OUT + ((size_t)tc*B_ + b)*H_ + j]       = acc0;
      out[O_OUT + ((size_t)tc*B_ + b)*H_ + j + 128] = acc1;
    }
  }
  if (p == 0) { // p_gen via folded dot products
    const float* cb = F + F_C3 + (tc%3)*BH + (size_t)b*H_;
    const float* xr = emb + ((size_t)b*T_ + tc)*E_;
    float part = 0.f;
#pragma unroll
    for (int jj2 = 0; jj2 < 7; ++jj2) {
      int i = tid + jj2*BLK;
      float v;
      if (i < 512)       v = pool[C_ACTX + i]     * pool[C_V1 + i];
      else if (i < 1024) v = pool[C_H2 + i - 512] * Wpg[i];
      else if (i < 1536) v = ald(cb + i - 1024)   * Wpg[i];
      else               v = xr[i - 1536]         * pool[C_V1 + 512 + (i - 1536)];
      part += v;
    }
    part = wred(part);
    if ((tid & 63) == 0) pool[C_TMP + (tid>>6)] = part;
    __syncthreads();
    if (tid == 0)
      out[O_PG + (size_t)tc*B_ + b] =
        sigm(pool[C_TMP]+pool[C_TMP+1]+pool[C_TMP+2]+pool[C_TMP+3] + pool[C_V1 + 768]);
  }
}

template<bool BF16>
__global__ __launch_bounds__(BLK, 2)
void decoder_kernel(const float* __restrict__ emb, const float* __restrict__ h0,
                    const float* __restrict__ c0, const float* __restrict__ ctx,
                    const float* __restrict__ Wih, const float* __restrict__ bih,
                    const float* __restrict__ Whh, const float* __restrict__ bhh,
                    const float* __restrict__ Wout, const float* __restrict__ bout,
                    const float* __restrict__ Wax, const float* __restrict__ bax,
                    const float* __restrict__ Wpg, const float* __restrict__ bpg,
                    float* __restrict__ out, float* __restrict__ F)
{
  __shared__ float pool[POOLSZ];
  unsigned* W = (unsigned*)F;
  const int tid = threadIdx.x, bid = blockIdx.x;
  unsigned ep = 0;

  // ---- phase 0 ----
  if (bid < 128) {             // init h/c slot 2 from h0,c0
    int i = bid*BLK + tid;
    ast(F + F_H3 + 2*BH + i, h0[i]);
    ast(F + F_C3 + 2*BH + i, c0[i]);
  }
  if (bid >= ABLK) {           // B-blocks: mask bias into LDS (persists; fp32 ctx)
    const int idx = bid - ABLK;
    const int b = idx / NCH, ch = idx - b*NCH;
    const int sb = (ch*S_)/NCH, se = ((ch+1)*S_)/NCH;
    const int w = tid >> 6, lane = tid & 63;
    for (int s = sb + w; s < se; s += 4) {
      const float* cr = ctx + ((size_t)b*S_ + s)*H_ + lane*8;
      float4 cA = *(const float4*)cr, cB = *(const float4*)(cr+4);
      float ssum = cA.x+cA.y+cA.z+cA.w+cB.x+cB.y+cB.z+cB.w;
      ssum = wred(ssum);
      if (lane == 0) pool[SB_BIAS + (s-sb)] = (ssum == 0.f) ? NEG_INF : 0.f;
    }
  }
  if (BF16) {                  // ctx -> bf16 copy (sc1 write-through stores)
    // total float4-pairs: B*S*H/8 = 4,194,304 = 131072 threads x 32 iters
    unsigned long long* dst = (unsigned long long*)(F + F_CTX16);
    size_t base = (size_t)bid*BLK + tid;
#pragma unroll 2
    for (int it = 0; it < 32; ++it) {
      size_t ci = base + (size_t)it*131072;
      const float4 v0 = *(const float4*)(ctx + ci*8);
      const float4 v1 = *(const float4*)(ctx + ci*8 + 4);
      unsigned long long lo = (unsigned long long)b16rne(v0.x)
        | ((unsigned long long)b16rne(v0.y) << 16)
        | ((unsigned long long)b16rne(v0.z) << 32)
        | ((unsigned long long)b16rne(v0.w) << 48);
      unsigned long long hi = (unsigned long long)b16rne(v1.x)
        | ((unsigned long long)b16rne(v1.y) << 16)
        | ((unsigned long long)b16rne(v1.z) << 32)
        | ((unsigned long long)b16rne(v1.w) << 48);
      ast64(dst + ci*2, lo);
      ast64(dst + ci*2 + 1, hi);
    }
  }
  if (bid < 5) {               // p_gen folds: V1, VX, S0
    const int w = tid>>6, lane = tid&63;
    const float* wp = Wpg + 1536 + lane*8;
    float4 wA = *(const float4*)wp, wB = *(const float4*)(wp+4);
    if (bid < 4) {
      for (int rr = 0; rr < 32; ++rr) {
        int k = bid*128 + rr*4 + w;
        const float* ar = Wax + (size_t)k*H_ + lane*8;
        float4 xA = *(const float4*)ar, xB = *(const float4*)(ar+4);
        float d = xA.x*wA.x+xA.y*wA.y+xA.z*wA.z+xA.w*wA.w
                + xB.x*wB.x+xB.y*wB.y+xB.z*wB.z+xB.w*wB.w;
        d = wred(d);
        if (lane == 0) ast(F + F_V1 + k, Wpg[k] + d);
      }
    } else {
      for (int rr = 0; rr < 64; ++rr) {
        int k = rr*4 + w;
        const float* ar = Wax + (size_t)(512+k)*H_ + lane*8;
        float4 xA = *(const float4*)ar, xB = *(const float4*)(ar+4);
        float d = xA.x*wA.x+xA.y*wA.y+xA.z*wA.z+xA.w*wA.w
                + xB.x*wB.x+xB.y*wB.y+xB.z*wB.z+xB.w*wB.w;
        d = wred(d);
        if (lane == 0) ast(F + F_VX + k, d);
      }
      if (tid < 64) {
        const float* br = bax + lane*8;
        float4 bA = *(const float4*)br, bB = *(const float4*)(br+4);
        float d = bA.x*wA.x+bA.y*wA.y+bA.z*wA.z+bA.w*wA.w
                + bB.x*wB.x+bB.y*wB.y+bB.z*wB.z+bB.w*wB.w;
        d = wred(d);
        if (lane == 0) ast(F + F_S0, bpg[0] + d);
      }
    }
  }
  gbar(W, ++ep);

  // stage p_gen folds into LDS once (A/C blocks; region persists above A's pool)
  if (bid < ABLK) {
    for (int i = tid; i < 769; i += BLK)
      pool[C_V1 + i] = ald(F + F_V1 + i);
  }

  // ---- prologue: A_0 ----
  if (bid < ABLK) do_A(0, bid, tid, emb, Wih, bih, Whh, bhh, F, pool);
  gbar(W, ++ep);

  // ---- main loop: one barrier per step; B_t || (A_{t+1}; C_{t-1}) ----
  for (int t = 0; t < T_; ++t) {
    if (bid >= ABLK) {
      do_B<BF16>(t, bid, tid, ctx, F, pool);
    } else {
      if (t < T_-1) do_A(t+1, bid, tid, emb, Wih, bih, Whh, bhh, F, pool);
      if (t > 0)    do_C(t-1, bid, tid, emb, Wout, bout, Wpg, out, F, pool);
    }
    gbar(W, ++ep);
  }

  // ---- epilogue: C_{T-1} + final h,c  (h_127 at slot 127%3 == 1) ----
  if (bid < ABLK) {
    do_C(T_-1, bid, tid, emb, Wout, bout, Wpg, out, F, pool);
  } else {
    const int idx = bid - ABLK;
    if (idx < 128) {
      int i = idx*BLK + tid;
      out[O_H + i] = ald(F + F_H3 + 1*BH + i);
    } else if (idx < 256) {
      int i = (idx-128)*BLK + tid;
      out[O_C + i] = ald(F + F_C3 + 1*BH + i);
    }
  }
}

extern "C" void kernel_launch(void* const* d_in, const int* in_sizes, int n_in,
                              void* d_out, int out_size, void* d_ws, size_t ws_size,
                              hipStream_t stream)
{
  if (ws_size < WS_MIN_BYTES) return;  // loud failure, no corruption
  hipMemsetAsync(d_ws, 0, U_TOTAL * sizeof(unsigned), stream);  // reset barrier flags
  if (ws_size >= WS_BF16_BYTES) {
    decoder_kernel<true><<<dim3(NBLK), dim3(BLK), 0, stream>>>(
        (const float*)d_in[0],  (const float*)d_in[1],  (const float*)d_in[2],
        (const float*)d_in[3],  (const float*)d_in[4],  (const float*)d_in[5],
        (const float*)d_in[6],  (const float*)d_in[7],  (const float*)d_in[8],
        (const float*)d_in[9],  (const float*)d_in[10], (const float*)d_in[11],
        (const float*)d_in[12], (const float*)d_in[13],
        (float*)d_out, (float*)d_ws);
  } else {
    decoder_kernel<false><<<dim3(NBLK), dim3(BLK), 0, stream>>>(
        (const float*)d_in[0],  (const float*)d_in[1],  (const float*)d_in[2],
        (const float*)d_in[3],  (const float*)d_in[4],  (const float*)d_in[5],
        (const float*)d_in[6],  (const float*)d_in[7],  (const float*)d_in[8],
        (const float*)d_in[9],  (const float*)d_in[10], (const float*)d_in[11],
        (const float*)d_in[12], (const float*)d_in[13],
        (float*)d_out, (float*)d_ws);
  }
}

// Round 8
// 7485.291 us; speedup vs baseline: 2.2044x; 2.2044x over previous
//
#include <hip/hip_runtime.h>

// Problem dims
#define T_ 128
#define B_ 64
#define E_ 256
#define H_ 512
#define S_ 1024
#define G_ 2048            // 4H
#define NCH 6              // attention s-chunks per batch row
#define NBLK 512
#define ABLK 128           // blocks doing LSTM (A) + output heads (C)
#define BLK 256
#define NGRP 16            // broadcast "go" lines
#define BH (B_*H_)
#define PSTR 520
#define PARTBUF (B_*NCH*PSTR)

// ---- barrier area (uint indices into ws) ----
#define U_ARR   256
#define U_TOTAL (U_ARR + NBLK*16)

// ws layout (float indices)
#define F_V1   8704                     // 512: Wpg[0:512] + Wax_top @ w4
#define F_VX   (F_V1 + 512)             // 256: Wax_bot @ w4
#define F_S0   (F_VX + 256)             // 1 (+63 pad)
#define F_H3   (F_S0 + 64)              // 3*B*H (h_t at slot t%3; h0 at slot 2)
#define F_C3   (F_H3 + 3*BH)
#define F_SC2  (F_C3 + 3*BH)            // 2*B*S raw scores (double buffer)
#define F_PART (F_SC2 + 2*B_*S_)        // 2*PARTBUF {m,l,pad6,ctx[512]}
#define F_CTX16 (F_PART + 2*PARTBUF)    // float idx where bf16 ctx copy begins
#define WS_MIN_BYTES ((size_t)F_CTX16*4)
#define WS_BF16_BYTES ((size_t)F_CTX16*4 + (size_t)B_*S_*H_*2)

// out layout (float indices)
#define O_OUT 0
#define O_H   ((size_t)T_*B_*H_)
#define O_C   (O_H + BH)
#define O_AD  (O_C + BH)
#define O_PG  (O_AD + (size_t)T_*B_*S_)

// LDS pool (floats). A: [0,5136). B: [0,2260). C: [5136,7200).
#define S_ACT   0        // A: 4 x 772 (x:0..256, h:256..768)
#define S_PART  3088     // A: 4 x 64 x 4
#define S_GATE  4112     // A: 4 x 256
#define SB_RED  0        // B: 4 x 520
#define SB_ML   2080     // B: 8
#define SB_BIAS 2088     // B: 172 (persists across steps on B-blocks)
#define C_ACTX  5136     // C: 512
#define C_H2    5648     // C: 512
#define C_PRT   6160     // C: 256
#define C_TMP   6416     // C: 8
#define C_V1    6424     // C: 769 (V1 512 | VX 256 | S0 1) — persists
#define POOLSZ  7200

#define NEG_INF (-__builtin_inff())

__device__ __forceinline__ float sigm(float x){ return 1.f/(1.f+__expf(-x)); }
__device__ __forceinline__ float tanh_(float x){ return 1.f - 2.f/(1.f+__expf(2.f*x)); }
__device__ __forceinline__ float wred(float v){
#pragma unroll
  for (int m = 1; m < 64; m <<= 1) v += __shfl_xor(v, m, 64);
  return v;
}
// device-coherent (sc1) access — for data mutated across blocks during the run
__device__ __forceinline__ float ald(const float* p){
  return __hip_atomic_load(p, __ATOMIC_RELAXED, __HIP_MEMORY_SCOPE_AGENT);
}
__device__ __forceinline__ void ast(float* p, float v){
  __hip_atomic_store(p, v, __ATOMIC_RELAXED, __HIP_MEMORY_SCOPE_AGENT);
}
__device__ __forceinline__ void ast64(unsigned long long* p, unsigned long long v){
  __hip_atomic_store(p, v, __ATOMIC_RELAXED, __HIP_MEMORY_SCOPE_AGENT);
}
__device__ __forceinline__ unsigned short b16rne(float f){
  unsigned u = __float_as_uint(f);
  unsigned r = u + 0x7fffu + ((u >> 16) & 1u);
  return (unsigned short)(r >> 16);
}
// unpack 2 bf16 from one u32 (little-endian packing: elem0 = low 16 bits)
__device__ __forceinline__ void unp(unsigned w, float& lo, float& hi){
  lo = __uint_as_float(w << 16);
  hi = __uint_as_float(w & 0xffff0000u);
}

// ---- fence-free grid barrier (512 blocks; sc1 data => no cache fences) ----
__device__ __forceinline__ void gbar(unsigned* W, unsigned ep){
  __syncthreads();
  const int tid = threadIdx.x, bid = blockIdx.x;
  if (tid == 0) {
    asm volatile("s_waitcnt vmcnt(0)" ::: "memory");
    __hip_atomic_store(&W[U_ARR + bid*16], ep, __ATOMIC_RELAXED, __HIP_MEMORY_SCOPE_AGENT);
  }
  if (bid == 0) {
    const int i0 = tid*2, i1 = i0+1;
    while (__hip_atomic_load(&W[U_ARR + i0*16], __ATOMIC_RELAXED, __HIP_MEMORY_SCOPE_AGENT) < ep)
      __builtin_amdgcn_s_sleep(2);
    while (__hip_atomic_load(&W[U_ARR + i1*16], __ATOMIC_RELAXED, __HIP_MEMORY_SCOPE_AGENT) < ep)
      __builtin_amdgcn_s_sleep(2);
    __syncthreads();
    if (tid < NGRP)
      __hip_atomic_store(&W[tid*16], ep, __ATOMIC_RELAXED, __HIP_MEMORY_SCOPE_AGENT);
  }
  if (tid == 0) {
    while (__hip_atomic_load(&W[(bid>>5)*16], __ATOMIC_RELAXED, __HIP_MEMORY_SCOPE_AGENT) < ep)
      __builtin_amdgcn_s_sleep(4);
  }
  __syncthreads();
}

// ---------------- Phase A: LSTM cell for step t ----------------
// 128 blocks = 16 bg (4 b) x 8 ug (64 units = 256 gate-cols).
// thread = (ks[7] bl[6:5] cq[4:0]): split-K x2, 2 float4 col-groups, unroll 8.
__device__ void do_A(int t, int bid, int tid,
                     const float* __restrict__ emb, const float* __restrict__ Wih,
                     const float* __restrict__ bih, const float* __restrict__ Whh,
                     const float* __restrict__ bhh, float* __restrict__ F,
                     float* __restrict__ pool)
{
  const int bg = bid >> 3, ug = bid & 7;
  { // stage act[bl][0:256)=x, [256:768)=h_{t-1}
    const int r = tid >> 6, i = tid & 63;
    const float* xr = emb + ((size_t)(bg*4 + r)*T_ + t)*E_ + i*4;
    *(float4*)(pool + S_ACT + r*772 + i*4) = *(const float4*)xr;
    const float* hsrc = F + F_H3 + ((t+2)%3)*BH + (size_t)(bg*4 + r)*H_ + i*8;
    float4 h0v, h1v;
    h0v.x=ald(hsrc+0); h0v.y=ald(hsrc+1); h0v.z=ald(hsrc+2); h0v.w=ald(hsrc+3);
    h1v.x=ald(hsrc+4); h1v.y=ald(hsrc+5); h1v.z=ald(hsrc+6); h1v.w=ald(hsrc+7);
    *(float4*)(pool + S_ACT + r*772 + 256 + i*8)     = h0v;
    *(float4*)(pool + S_ACT + r*772 + 256 + i*8 + 4) = h1v;
  }
  __syncthreads();
  const int ks = tid >> 7, bl = (tid >> 5) & 3, cq = tid & 31;
  const int cgi1 = cq, cgi2 = cq + 32;
  const int col1 = ((cgi1 >> 4) << 9) + ug*64 + ((cgi1 & 15) << 2);
  const int col2 = ((cgi2 >> 4) << 9) + ug*64 + ((cgi2 & 15) << 2);
  float4 A1, A2;
  if (ks == 0) {
    const float4 x1 = *(const float4*)(bih + col1), y1 = *(const float4*)(bhh + col1);
    const float4 x2 = *(const float4*)(bih + col2), y2 = *(const float4*)(bhh + col2);
    A1.x=x1.x+y1.x; A1.y=x1.y+y1.y; A1.z=x1.z+y1.z; A1.w=x1.w+y1.w;
    A2.x=x2.x+y2.x; A2.y=x2.y+y2.y; A2.z=x2.z+y2.z; A2.w=x2.w+y2.w;
  } else { A1.x=A1.y=A1.z=A1.w=0.f; A2.x=A2.y=A2.z=A2.w=0.f; }
  const float* ap = pool + S_ACT + bl*772;
  if (ks == 0) {
    const float* w1 = Wih + col1; const float* w2 = Wih + col2;
#pragma unroll 8
    for (int k = 0; k < 256; ++k) {
      float a = ap[k];
      float4 v1 = *(const float4*)(w1 + (size_t)k*G_);
      float4 v2 = *(const float4*)(w2 + (size_t)k*G_);
      A1.x=fmaf(a,v1.x,A1.x); A1.y=fmaf(a,v1.y,A1.y); A1.z=fmaf(a,v1.z,A1.z); A1.w=fmaf(a,v1.w,A1.w);
      A2.x=fmaf(a,v2.x,A2.x); A2.y=fmaf(a,v2.y,A2.y); A2.z=fmaf(a,v2.z,A2.z); A2.w=fmaf(a,v2.w,A2.w);
    }
    const float* u1 = Whh + col1; const float* u2 = Whh + col2;
    const float* ap2 = ap + 256;
#pragma unroll 8
    for (int k = 0; k < 128; ++k) {
      float a = ap2[k];
      float4 v1 = *(const float4*)(u1 + (size_t)k*G_);
      float4 v2 = *(const float4*)(u2 + (size_t)k*G_);
      A1.x=fmaf(a,v1.x,A1.x); A1.y=fmaf(a,v1.y,A1.y); A1.z=fmaf(a,v1.z,A1.z); A1.w=fmaf(a,v1.w,A1.w);
      A2.x=fmaf(a,v2.x,A2.x); A2.y=fmaf(a,v2.y,A2.y); A2.z=fmaf(a,v2.z,A2.z); A2.w=fmaf(a,v2.w,A2.w);
    }
  } else {
    const float* u1 = Whh + (size_t)128*G_ + col1; const float* u2 = Whh + (size_t)128*G_ + col2;
    const float* ap2 = ap + 384;
#pragma unroll 8
    for (int k = 0; k < 384; ++k) {
      float a = ap2[k];
      float4 v1 = *(const float4*)(u1 + (size_t)k*G_);
      float4 v2 = *(const float4*)(u2 + (size_t)k*G_);
      A1.x=fmaf(a,v1.x,A1.x); A1.y=fmaf(a,v1.y,A1.y); A1.z=fmaf(a,v1.z,A1.z); A1.w=fmaf(a,v1.w,A1.w);
      A2.x=fmaf(a,v2.x,A2.x); A2.y=fmaf(a,v2.y,A2.y); A2.z=fmaf(a,v2.z,A2.z); A2.w=fmaf(a,v2.w,A2.w);
    }
  }
  if (ks == 1) {
    *(float4*)(pool + S_PART + ((bl*64 + cgi1) << 2)) = A1;
    *(float4*)(pool + S_PART + ((bl*64 + cgi2) << 2)) = A2;
  }
  __syncthreads();
  if (ks == 0) {
    const float4 P1 = *(const float4*)(pool + S_PART + ((bl*64 + cgi1) << 2));
    const float4 P2 = *(const float4*)(pool + S_PART + ((bl*64 + cgi2) << 2));
    A1.x+=P1.x; A1.y+=P1.y; A1.z+=P1.z; A1.w+=P1.w;
    A2.x+=P2.x; A2.y+=P2.y; A2.z+=P2.z; A2.w+=P2.w;
    *(float4*)(pool + S_GATE + bl*256 + (cgi1 << 2)) = A1;
    *(float4*)(pool + S_GATE + bl*256 + (cgi2 << 2)) = A2;
  }
  __syncthreads();
  { // nonlinearity: thread = (bl2, unit)
    const int bl2 = tid >> 6, ul = tid & 63;
    const int b2 = bg*4 + bl2, uu = ug*64 + ul;
    float gi = pool[S_GATE + bl2*256 + ul];
    float gf = pool[S_GATE + bl2*256 + 64 + ul];
    float gg = pool[S_GATE + bl2*256 + 128 + ul];
    float go = pool[S_GATE + bl2*256 + 192 + ul];
    float cp = ald(F + F_C3 + ((t+2)%3)*BH + (size_t)b2*H_ + uu);
    float cn = sigm(gf)*cp + sigm(gi)*tanh_(gg);
    float hn = sigm(go)*tanh_(cn);
    ast(F + F_H3 + (t%3)*BH + (size_t)b2*H_ + uu, hn);
    ast(F + F_C3 + (t%3)*BH + (size_t)b2*H_ + uu, cn);
  }
}

// ---------------- Phase B: single-pass attention partials for step t ----------------
// BF16 path: no-max softmax (scores bounded; exp clamped at 80) -> no sequential
// rescale; 8-row groups with all 8 loads hoisted -> 128B/thread (8KB/wave) in
// flight vs 64B before. Partials {m=0,l}; do_C's generic merge handles it.
template<bool BF16>
__device__ void do_B(int t, int bid, int tid, const float* __restrict__ ctx,
                     float* __restrict__ F, float* __restrict__ pool)
{
  const int idx = bid - ABLK;
  const int b = idx / NCH, ch = idx - b*NCH;
  const int sb = (ch*S_)/NCH, se = ((ch+1)*S_)/NCH;
  const int w = tid >> 6, lane = tid & 63;
  const float* hb = F + F_H3 + (t%3)*BH + (size_t)b*H_ + lane*8;
  float h0_=ald(hb+0), h1_=ald(hb+1), h2_=ald(hb+2), h3_=ald(hb+3),
        h4_=ald(hb+4), h5_=ald(hb+5), h6_=ald(hb+6), h7_=ald(hb+7);
  float* scw = F + F_SC2 + (size_t)(t&1)*(B_*S_) + (size_t)b*S_;
  const float* s_bias = pool + SB_BIAS;

  if (BF16) {
    const uint4* c16v = (const uint4*)(F + F_CTX16) + (size_t)b*S_*64 + lane;
    float l = 0.f;
    float a0=0,a1=0,a2=0,a3=0,a4=0,a5=0,a6=0,a7=0;
    for (int s0 = sb + w*8; s0 < se; s0 += 32) {
      uint4 q[8];
#pragma unroll
      for (int i = 0; i < 8; ++i) {          // all 8 loads in flight
        int s = s0 + i;
        int ss = (s < se) ? s : sb;
        q[i] = c16v[(size_t)ss*64];
      }
      float d[8];
#pragma unroll
      for (int i = 0; i < 8; ++i) {
        float c0,c1,c2,c3,c4,c5,c6,c7;
        unp(q[i].x,c0,c1); unp(q[i].y,c2,c3); unp(q[i].z,c4,c5); unp(q[i].w,c6,c7);
        d[i] = c0*h0_+c1*h1_+c2*h2_+c3*h3_+c4*h4_+c5*h5_+c6*h6_+c7*h7_;
      }
#pragma unroll
      for (int mm = 1; mm < 64; mm <<= 1) {  // 8 independent pipelined chains
        d[0]+=__shfl_xor(d[0],mm,64); d[1]+=__shfl_xor(d[1],mm,64);
        d[2]+=__shfl_xor(d[2],mm,64); d[3]+=__shfl_xor(d[3],mm,64);
        d[4]+=__shfl_xor(d[4],mm,64); d[5]+=__shfl_xor(d[5],mm,64);
        d[6]+=__shfl_xor(d[6],mm,64); d[7]+=__shfl_xor(d[7],mm,64);
      }
      float wg[8];
#pragma unroll
      for (int i = 0; i < 8; ++i) {
        int s = s0 + i;
        bool v = (s < se);
        float bias = v ? s_bias[s - sb] : NEG_INF;
        float sc = d[i] + bias;
        if (lane == 0 && v) ast(scw + s, sc);
        wg[i] = (bias == 0.f) ? __expf(fminf(sc, 80.f)) : 0.f;
        l += wg[i];
      }
#pragma unroll
      for (int i = 0; i < 8; ++i) {
        float c0,c1,c2,c3,c4,c5,c6,c7;
        unp(q[i].x,c0,c1); unp(q[i].y,c2,c3); unp(q[i].z,c4,c5); unp(q[i].w,c6,c7);
        a0=fmaf(wg[i],c0,a0); a1=fmaf(wg[i],c1,a1); a2=fmaf(wg[i],c2,a2); a3=fmaf(wg[i],c3,a3);
        a4=fmaf(wg[i],c4,a4); a5=fmaf(wg[i],c5,a5); a6=fmaf(wg[i],c6,a6); a7=fmaf(wg[i],c7,a7);
      }
    }
    if (lane == 0) pool[SB_ML + w] = l;
    { float* r = pool + SB_RED + w*520 + lane*8;
      r[0]=a0; r[1]=a1; r[2]=a2; r[3]=a3; r[4]=a4; r[5]=a5; r[6]=a6; r[7]=a7; }
    __syncthreads();
    float lb = pool[SB_ML+0]+pool[SB_ML+1]+pool[SB_ML+2]+pool[SB_ML+3];
    float* Pp = F + F_PART + (size_t)(t&1)*PARTBUF + (size_t)(b*NCH+ch)*PSTR;
    for (int u = tid; u < H_; u += BLK)
      ast(Pp + 8 + u, pool[SB_RED + 0*520 + u] + pool[SB_RED + 1*520 + u]
                    + pool[SB_RED + 2*520 + u] + pool[SB_RED + 3*520 + u]);
    if (tid == 0) { ast(Pp+0, 0.f); ast(Pp+1, lb); }
    return;
  }

  // ---- fp32 fallback: old 4-row online-softmax path ----
  const float* cbase = ctx + (size_t)b*S_*H_ + lane*8;
  float m = NEG_INF, l = 0.f;
  float a0=0,a1=0,a2=0,a3=0,a4=0,a5=0,a6=0,a7=0;
  for (int s0 = sb + w*4; s0 < se; s0 += 16) {
    float cv[4][8]; float d[4];
#pragma unroll
    for (int i = 0; i < 4; ++i) {
      int s = s0 + i;
      const float* cr = cbase + (size_t)(s < se ? s : sb)*H_;
      float4 cA = *(const float4*)cr, cB = *(const float4*)(cr + 4);
      cv[i][0]=cA.x; cv[i][1]=cA.y; cv[i][2]=cA.z; cv[i][3]=cA.w;
      cv[i][4]=cB.x; cv[i][5]=cB.y; cv[i][6]=cB.z; cv[i][7]=cB.w;
    }
#pragma unroll
    for (int i = 0; i < 4; ++i)
      d[i] = cv[i][0]*h0_ + cv[i][1]*h1_ + cv[i][2]*h2_ + cv[i][3]*h3_
           + cv[i][4]*h4_ + cv[i][5]*h5_ + cv[i][6]*h6_ + cv[i][7]*h7_;
#pragma unroll
    for (int mm = 1; mm < 64; mm <<= 1) {
      d[0] += __shfl_xor(d[0], mm, 64); d[1] += __shfl_xor(d[1], mm, 64);
      d[2] += __shfl_xor(d[2], mm, 64); d[3] += __shfl_xor(d[3], mm, 64);
    }
    float sc[4];
#pragma unroll
    for (int i = 0; i < 4; ++i) {
      int s = s0 + i;
      sc[i] = (s < se) ? d[i] + s_bias[s - sb] : NEG_INF;
      if (lane == 0 && s < se) ast(scw + s, sc[i]);
    }
    float mx = fmaxf(fmaxf(sc[0],sc[1]), fmaxf(sc[2],sc[3]));
    float mn = fmaxf(m, mx);
    float al = (mn == m) ? 1.f : __expf(m - mn);
    float w0 = (sc[0]==NEG_INF)?0.f:__expf(sc[0]-mn);
    float w1 = (sc[1]==NEG_INF)?0.f:__expf(sc[1]-mn);
    float w2 = (sc[2]==NEG_INF)?0.f:__expf(sc[2]-mn);
    float w3 = (sc[3]==NEG_INF)?0.f:__expf(sc[3]-mn);
    l = l*al + (w0+w1+w2+w3);
    a0 = a0*al + w0*cv[0][0] + w1*cv[1][0] + w2*cv[2][0] + w3*cv[3][0];
    a1 = a1*al + w0*cv[0][1] + w1*cv[1][1] + w2*cv[2][1] + w3*cv[3][1];
    a2 = a2*al + w0*cv[0][2] + w1*cv[1][2] + w2*cv[2][2] + w3*cv[3][2];
    a3 = a3*al + w0*cv[0][3] + w1*cv[1][3] + w2*cv[2][3] + w3*cv[3][3];
    a4 = a4*al + w0*cv[0][4] + w1*cv[1][4] + w2*cv[2][4] + w3*cv[3][4];
    a5 = a5*al + w0*cv[0][5] + w1*cv[1][5] + w2*cv[2][5] + w3*cv[3][5];
    a6 = a6*al + w0*cv[0][6] + w1*cv[1][6] + w2*cv[2][6] + w3*cv[3][6];
    a7 = a7*al + w0*cv[0][7] + w1*cv[1][7] + w2*cv[2][7] + w3*cv[3][7];
    m = mn;
  }
  if (lane == 0) { pool[SB_ML + w*2] = m; pool[SB_ML + w*2+1] = l; }
  { float* r = pool + SB_RED + w*520 + lane*8;
    r[0]=a0; r[1]=a1; r[2]=a2; r[3]=a3; r[4]=a4; r[5]=a5; r[6]=a6; r[7]=a7; }
  __syncthreads();
  float m0=pool[SB_ML+0], l0=pool[SB_ML+1], m1=pool[SB_ML+2], l1=pool[SB_ML+3],
        m2=pool[SB_ML+4], l2=pool[SB_ML+5], m3=pool[SB_ML+6], l3=pool[SB_ML+7];
  float mb = fmaxf(fmaxf(m0,m1), fmaxf(m2,m3));
  float k0 = (l0>0.f) ? __expf(m0-mb) : 0.f;
  float k1 = (l1>0.f) ? __expf(m1-mb) : 0.f;
  float k2 = (l2>0.f) ? __expf(m2-mb) : 0.f;
  float k3 = (l3>0.f) ? __expf(m3-mb) : 0.f;
  float lb = k0*l0 + k1*l1 + k2*l2 + k3*l3;
  float* Pp = F + F_PART + (size_t)(t&1)*PARTBUF + (size_t)(b*NCH+ch)*PSTR;
  for (int u = tid; u < H_; u += BLK)
    ast(Pp + 8 + u, k0*pool[SB_RED + 0*520 + u] + k1*pool[SB_RED + 1*520 + u]
                  + k2*pool[SB_RED + 2*520 + u] + k3*pool[SB_RED + 3*520 + u]);
  if (tid == 0) { ast(Pp+0, mb); ast(Pp+1, lb); }
}

// ---------------- Phase C: outputs for step tc ----------------
// 128 blocks: b = bid>>1, p = bid&1 (256-col slice). split-K x2 + 2 cols/thread.
__device__ void do_C(int tc, int bid, int tid,
                     const float* __restrict__ emb, const float* __restrict__ Wout,
                     const float* __restrict__ bout, const float* __restrict__ Wpg,
                     float* __restrict__ out, float* __restrict__ F,
                     float* __restrict__ pool)
{
  const int b = bid >> 1, p = bid & 1;
  const float* P0 = F + F_PART + (size_t)(tc&1)*PARTBUF + (size_t)(b*NCH)*PSTR;
  float mk[NCH], lk[NCH], ck[NCH];
  float mb = NEG_INF;
#pragma unroll
  for (int k = 0; k < NCH; ++k) { mk[k]=ald(P0+k*PSTR); lk[k]=ald(P0+k*PSTR+1); mb=fmaxf(mb,mk[k]); }
  float lb = 0.f;
#pragma unroll
  for (int k = 0; k < NCH; ++k) { ck[k] = (lk[k]>0.f) ? __expf(mk[k]-mb) : 0.f; lb += ck[k]*lk[k]; }
  float inv = 1.f/lb;
  { // merge partial contexts -> actx ; stage h
    int u = tid;
    float v0 = 0.f, v1 = 0.f;
#pragma unroll
    for (int k = 0; k < NCH; ++k) {
      v0 += ck[k]*ald(P0 + k*PSTR + 8 + u);
      v1 += ck[k]*ald(P0 + k*PSTR + 8 + u + 256);
    }
    pool[C_ACTX + u]       = v0*inv;
    pool[C_ACTX + u + 256] = v1*inv;
    const float* hsrc = F + F_H3 + (tc%3)*BH + (size_t)b*H_;
    pool[C_H2 + tid]       = ald(hsrc + tid);
    pool[C_H2 + tid + 256] = ald(hsrc + tid + 256);
  }
  __syncthreads();
  { // attention distribution (this block's 512-col slice of S)
    const float* scr = F + F_SC2 + (size_t)(tc&1)*(B_*S_) + (size_t)b*S_;
    float* ad = out + O_AD + ((size_t)tc*B_ + b)*S_;
    int s = p*512 + tid;
    ad[s] = __expf(ald(scr+s)-mb)*inv;
    s += 256;
    ad[s] = __expf(ald(scr+s)-mb)*inv;
  }
  { // out = [attn_ctx, h] @ W_out + b_out : kh=0 -> actx rows, kh=1 -> h rows
    const int kh = tid >> 7, jj = tid & 127;
    const int j = p*256 + jj;
    float acc0 = (kh == 0) ? bout[j]     : 0.f;
    float acc1 = (kh == 0) ? bout[j+128] : 0.f;
    const float* src = (kh == 0) ? (pool + C_ACTX) : (pool + C_H2);
    const float* wq = Wout + (size_t)(kh*512)*H_ + j;
#pragma unroll 8
    for (int k = 0; k < 512; ++k) {
      float s = src[k];
      const float* r = wq + (size_t)k*H_;
      acc0 = fmaf(s, r[0],   acc0);
      acc1 = fmaf(s, r[128], acc1);
    }
    if (kh == 1) { pool[C_PRT + jj*2] = acc0; pool[C_PRT + jj*2 + 1] = acc1; }
    __syncthreads();
    if (kh == 0) {
      acc0 += pool[C_PRT + jj*2];
      acc1 += pool[C_PRT + jj*2 + 1];
      out[O_OUT + ((size_t)tc*B_ + b)*H_ + j]       = acc0;
      out[O_OUT + ((size_t)tc*B_ + b)*H_ + j + 128] = acc1;
    }
  }
  if (p == 0) { // p_gen via folded dot products
    const float* cb = F + F_C3 + (tc%3)*BH + (size_t)b*H_;
    const float* xr = emb + ((size_t)b*T_ + tc)*E_;
    float part = 0.f;
#pragma unroll
    for (int jj2 = 0; jj2 < 7; ++jj2) {
      int i = tid + jj2*BLK;
      float v;
      if (i < 512)       v = pool[C_ACTX + i]     * pool[C_V1 + i];
      else if (i < 1024) v = pool[C_H2 + i - 512] * Wpg[i];
      else if (i < 1536) v = ald(cb + i - 1024)   * Wpg[i];
      else               v = xr[i - 1536]         * pool[C_V1 + 512 + (i - 1536)];
      part += v;
    }
    part = wred(part);
    if ((tid & 63) == 0) pool[C_TMP + (tid>>6)] = part;
    __syncthreads();
    if (tid == 0)
      out[O_PG + (size_t)tc*B_ + b] =
        sigm(pool[C_TMP]+pool[C_TMP+1]+pool[C_TMP+2]+pool[C_TMP+3] + pool[C_V1 + 768]);
  }
}

template<bool BF16>
__global__ __launch_bounds__(BLK, 2)
void decoder_kernel(const float* __restrict__ emb, const float* __restrict__ h0,
                    const float* __restrict__ c0, const float* __restrict__ ctx,
                    const float* __restrict__ Wih, const float* __restrict__ bih,
                    const float* __restrict__ Whh, const float* __restrict__ bhh,
                    const float* __restrict__ Wout, const float* __restrict__ bout,
                    const float* __restrict__ Wax, const float* __restrict__ bax,
                    const float* __restrict__ Wpg, const float* __restrict__ bpg,
                    float* __restrict__ out, float* __restrict__ F)
{
  __shared__ float pool[POOLSZ];
  unsigned* W = (unsigned*)F;
  const int tid = threadIdx.x, bid = blockIdx.x;
  unsigned ep = 0;

  // ---- phase 0 ----
  if (bid < 128) {             // init h/c slot 2 from h0,c0
    int i = bid*BLK + tid;
    ast(F + F_H3 + 2*BH + i, h0[i]);
    ast(F + F_C3 + 2*BH + i, c0[i]);
  }
  if (bid >= ABLK) {           // B-blocks: mask bias into LDS (persists; fp32 ctx)
    const int idx = bid - ABLK;
    const int b = idx / NCH, ch = idx - b*NCH;
    const int sb = (ch*S_)/NCH, se = ((ch+1)*S_)/NCH;
    const int w = tid >> 6, lane = tid & 63;
    for (int s = sb + w; s < se; s += 4) {
      const float* cr = ctx + ((size_t)b*S_ + s)*H_ + lane*8;
      float4 cA = *(const float4*)cr, cB = *(const float4*)(cr+4);
      float ssum = cA.x+cA.y+cA.z+cA.w+cB.x+cB.y+cB.z+cB.w;
      ssum = wred(ssum);
      if (lane == 0) pool[SB_BIAS + (s-sb)] = (ssum == 0.f) ? NEG_INF : 0.f;
    }
  }
  if (BF16) {                  // ctx -> bf16 copy (sc1 write-through stores)
    // total float4-pairs: B*S*H/8 = 4,194,304 = 131072 threads x 32 iters
    unsigned long long* dst = (unsigned long long*)(F + F_CTX16);
    size_t base = (size_t)bid*BLK + tid;
#pragma unroll 2
    for (int it = 0; it < 32; ++it) {
      size_t ci = base + (size_t)it*131072;
      const float4 v0 = *(const float4*)(ctx + ci*8);
      const float4 v1 = *(const float4*)(ctx + ci*8 + 4);
      unsigned long long lo = (unsigned long long)b16rne(v0.x)
        | ((unsigned long long)b16rne(v0.y) << 16)
        | ((unsigned long long)b16rne(v0.z) << 32)
        | ((unsigned long long)b16rne(v0.w) << 48);
      unsigned long long hi = (unsigned long long)b16rne(v1.x)
        | ((unsigned long long)b16rne(v1.y) << 16)
        | ((unsigned long long)b16rne(v1.z) << 32)
        | ((unsigned long long)b16rne(v1.w) << 48);
      ast64(dst + ci*2, lo);
      ast64(dst + ci*2 + 1, hi);
    }
  }
  if (bid < 5) {               // p_gen folds: V1, VX, S0
    const int w = tid>>6, lane = tid&63;
    const float* wp = Wpg + 1536 + lane*8;
    float4 wA = *(const float4*)wp, wB = *(const float4*)(wp+4);
    if (bid < 4) {
      for (int rr = 0; rr < 32; ++rr) {
        int k = bid*128 + rr*4 + w;
        const float* ar = Wax + (size_t)k*H_ + lane*8;
        float4 xA = *(const float4*)ar, xB = *(const float4*)(ar+4);
        float d = xA.x*wA.x+xA.y*wA.y+xA.z*wA.z+xA.w*wA.w
                + xB.x*wB.x+xB.y*wB.y+xB.z*wB.z+xB.w*wB.w;
        d = wred(d);
        if (lane == 0) ast(F + F_V1 + k, Wpg[k] + d);
      }
    } else {
      for (int rr = 0; rr < 64; ++rr) {
        int k = rr*4 + w;
        const float* ar = Wax + (size_t)(512+k)*H_ + lane*8;
        float4 xA = *(const float4*)ar, xB = *(const float4*)(ar+4);
        float d = xA.x*wA.x+xA.y*wA.y+xA.z*wA.z+xA.w*wA.w
                + xB.x*wB.x+xB.y*wB.y+xB.z*wB.z+xB.w*wB.w;
        d = wred(d);
        if (lane == 0) ast(F + F_VX + k, d);
      }
      if (tid < 64) {
        const float* br = bax + lane*8;
        float4 bA = *(const float4*)br, bB = *(const float4*)(br+4);
        float d = bA.x*wA.x+bA.y*wA.y+bA.z*wA.z+bA.w*wA.w
                + bB.x*wB.x+bB.y*wB.y+bB.z*wB.z+bB.w*wB.w;
        d = wred(d);
        if (lane == 0) ast(F + F_S0, bpg[0] + d);
      }
    }
  }
  gbar(W, ++ep);

  // stage p_gen folds into LDS once (A/C blocks; region persists above A's pool)
  if (bid < ABLK) {
    for (int i = tid; i < 769; i += BLK)
      pool[C_V1 + i] = ald(F + F_V1 + i);
  }

  // ---- prologue: A_0 ----
  if (bid < ABLK) do_A(0, bid, tid, emb, Wih, bih, Whh, bhh, F, pool);
  gbar(W, ++ep);

  // ---- main loop: one barrier per step; B_t || (A_{t+1}; C_{t-1}) ----
  for (int t = 0; t < T_; ++t) {
    if (bid >= ABLK) {
      do_B<BF16>(t, bid, tid, ctx, F, pool);
    } else {
      if (t < T_-1) do_A(t+1, bid, tid, emb, Wih, bih, Whh, bhh, F, pool);
      if (t > 0)    do_C(t-1, bid, tid, emb, Wout, bout, Wpg, out, F, pool);
    }
    gbar(W, ++ep);
  }

  // ---- epilogue: C_{T-1} + final h,c  (h_127 at slot 127%3 == 1) ----
  if (bid < ABLK) {
    do_C(T_-1, bid, tid, emb, Wout, bout, Wpg, out, F, pool);
  } else {
    const int idx = bid - ABLK;
    if (idx < 128) {
      int i = idx*BLK + tid;
      out[O_H + i] = ald(F + F_H3 + 1*BH + i);
    } else if (idx < 256) {
      int i = (idx-128)*BLK + tid;
      out[O_C + i] = ald(F + F_C3 + 1*BH + i);
    }
  }
}

extern "C" void kernel_launch(void* const* d_in, const int* in_sizes, int n_in,
                              void* d_out, int out_size, void* d_ws, size_t ws_size,
                              hipStream_t stream)
{
  if (ws_size < WS_MIN_BYTES) return;  // loud failure, no corruption
  hipMemsetAsync(d_ws, 0, U_TOTAL * sizeof(unsigned), stream);  // reset barrier flags
  if (ws_size >= WS_BF16_BYTES) {
    decoder_kernel<true><<<dim3(NBLK), dim3(BLK), 0, stream>>>(
        (const float*)d_in[0],  (const float*)d_in[1],  (const float*)d_in[2],
        (const float*)d_in[3],  (const float*)d_in[4],  (const float*)d_in[5],
        (const float*)d_in[6],  (const float*)d_in[7],  (const float*)d_in[8],
        (const float*)d_in[9],  (const float*)d_in[10], (const float*)d_in[11],
        (const float*)d_in[12], (const float*)d_in[13],
        (float*)d_out, (float*)d_ws);
  } else {
    decoder_kernel<false><<<dim3(NBLK), dim3(BLK), 0, stream>>>(
        (const float*)d_in[0],  (const float*)d_in[1],  (const float*)d_in[2],
        (const float*)d_in[3],  (const float*)d_in[4],  (const float*)d_in[5],
        (const float*)d_in[6],  (const float*)d_in[7],  (const float*)d_in[8],
        (const float*)d_in[9],  (const float*)d_in[10], (const float*)d_in[11],
        (const float*)d_in[12], (const float*)d_in[13],
        (float*)d_out, (float*)d_ws);
  }
}